// Round 11
// baseline (224.629 us; speedup 1.0000x reference)
//
#include <hip/hip_runtime.h>
#include <hip/hip_bf16.h>

#define EPS_BN 1e-5f

typedef __attribute__((ext_vector_type(8))) short short8;   // 8 x bf16 (4 VGPR)
typedef __attribute__((ext_vector_type(4))) float float4v;  // MFMA acc

constexpr int NGROUPS    = 65536;     // B*P = 16*4096
constexpr int NEWX_ELEMS = 196608;    // B*P*3
constexpr int GRID       = 4096;      // blocks of 256 (4 waves); 16384 waves
constexpr int GITER      = NGROUPS / (GRID * 4);  // 4 groups per wave
constexpr int GSTRIDE    = GRID * 4;

// d_ws layout: f32 indices for folded f32 data, byte offsets for bf16 weights
constexpr int W0F = 0;      // f32[192]  W0' (64x3)
constexpr int B0F = 192;    // f32[64]
constexpr int B1F = 256;    // f32[64]
constexpr int B2F = 320;    // f32[128]
constexpr int W1B = 1792;   // bytes: ushort[4096]  W1' (64x64) bf16
constexpr int W2B = 10240;  // bytes: ushort[8192]  W2' (128x64) bf16

__device__ __forceinline__ unsigned short f2bf(float x) {
    return __builtin_bit_cast(unsigned short, __float2bfloat16(x));
}
// HW packed convert: dst.lo16 = bf16(a), dst.hi16 = bf16(b).
__device__ __forceinline__ unsigned cvtpk(float a, float b) {
    unsigned r;
    asm("v_cvt_pk_bf16_f32 %0, %1, %2" : "=v"(r) : "v"(a), "v"(b));
    return r;
}

__global__ void fold_kernel(
    const float* w0, const float* b0, const float* g0,
    const float* be0, const float* m0, const float* v0,
    const float* w1, const float* b1, const float* g1,
    const float* be1, const float* m1, const float* v1,
    const float* w2, const float* b2, const float* g2,
    const float* be2, const float* m2, const float* v2,
    float* __restrict__ ws)
{
    const int t = threadIdx.x;
    ushort* w1b = (ushort*)((char*)ws + W1B);
    ushort* w2b = (ushort*)((char*)ws + W2B);
    if (t < 64) {
        float s0 = g0[t] * rsqrtf(v0[t] + EPS_BN);
        ws[B0F + t] = (b0[t] - m0[t]) * s0 + be0[t];
        ws[W0F + t*3 + 0] = w0[t*3 + 0] * s0;
        ws[W0F + t*3 + 1] = w0[t*3 + 1] * s0;
        ws[W0F + t*3 + 2] = w0[t*3 + 2] * s0;
        float s1 = g1[t] * rsqrtf(v1[t] + EPS_BN);
        ws[B1F + t] = (b1[t] - m1[t]) * s1 + be1[t];
    }
    if (t < 128) {
        float s2 = g2[t] * rsqrtf(v2[t] + EPS_BN);
        ws[B2F + t] = (b2[t] - m2[t]) * s2 + be2[t];
    }
    for (int i = t; i < 64*64; i += 256) {
        int o = i >> 6;
        float s = g1[o] * rsqrtf(v1[o] + EPS_BN);
        w1b[i] = f2bf(w1[i] * s);
    }
    for (int i = t; i < 128*64; i += 256) {
        int o = i >> 6;
        float s = g2[o] * rsqrtf(v2[o] + EPS_BN);
        w2b[i] = f2bf(w2[i] * s);
    }
}

// new_x passthrough, f32 -> f32
__global__ void copy_new_x(const float4* __restrict__ in, float4* __restrict__ out)
{
    int i = blockIdx.x * 256 + threadIdx.x;   // < 49,152
    out[i] = in[i];
}

// One wave = one group. Single 4KB H tile per wave (16KB/block total; no
// block-shared state, ZERO barriers). W2 fragments are read from GLOBAL
// (12KB, L2/L3-resident) in the n-loop instead of LDS: R10 counters showed
// the per-group re-read of all of W2 from LDS was ~40% of a half-saturated
// DS pipe, and 32KB LDS capped residency. 16KB LDS + VGPR~64 lets HW
// occupancy float to 8 waves/SIMD (launch_bounds 2nd arg is a MINIMUM).
__global__ __launch_bounds__(256, 4) void sa_mfma_kernel(
    const float* __restrict__ xg,
    const float* __restrict__ wsf,
    float* __restrict__ feats)
{
    __shared__ __align__(16) ushort Hs[4][2048];    // 4 waves x 4KB

    const int tid = threadIdx.x;
    const int w   = tid >> 6;
    const int l   = tid & 63;
    const int l15 = l & 15;
    const int lhi = l >> 4;

    const ushort* w1b = (const ushort*)((const char*)wsf + W1B);
    const ushort* w2b = (const ushort*)((const char*)wsf + W2B);

    ushort* H = Hs[w];
    const short8  zero8 = {0,0,0,0,0,0,0,0};
    const float4v zero4 = {0.f, 0.f, 0.f, 0.f};

    // ---- hoisted weight fragments (b0f, b1f; W2 read per-group from L2) ----
    short8 b0f[4];
#pragma unroll
    for (int mt = 0; mt < 4; ++mt) {
        union { short8 v; unsigned d[4]; } f;
        f.v = zero8;
        if (lhi == 0) {
            int o = 16*mt + l15;
            f.d[0] = cvtpk(wsf[W0F + o*3 + 0], wsf[W0F + o*3 + 1]);
            f.d[1] = cvtpk(wsf[W0F + o*3 + 2], wsf[B0F + o]);
        }
        b0f[mt] = f.v;
    }
    short8 b1f[2][4];
#pragma unroll
    for (int ks = 0; ks < 2; ++ks)
#pragma unroll
        for (int mt = 0; mt < 4; ++mt)
            b1f[ks][mt] = *(const short8*)&w1b[(16*mt + l15)*64 + 32*ks + 8*lhi];

    float4v b1vv[4];   // bias for h2 channels o = 16mt + 4lhi + i (acc layout)
#pragma unroll
    for (int mt = 0; mt < 4; ++mt)
        b1vv[mt] = *(const float4v*)&wsf[B1F + 16*mt + 4*lhi];
    float b2v[8];      // bias for output channels 16n + l15
#pragma unroll
    for (int n = 0; n < 8; ++n)
        b2v[n] = wsf[B2F + 16*n + l15];

    const int wid = blockIdx.x * 4 + w;
    // per-lane base for W2 fragment loads: row l15, byte-chunk lhi
    const ushort* w2p = w2b + (size_t)l15*64 + 8*lhi;

    // prefetch first group's x (lanes lhi==0: sample = 16nt + l15)
    float xr[2][3];
#pragma unroll
    for (int nt = 0; nt < 2; ++nt)
        if (lhi == 0) {
            const float* xp = xg + ((size_t)wid*32 + 16*nt + l15) * 3;
            xr[nt][0] = xp[0]; xr[nt][1] = xp[1]; xr[nt][2] = xp[2];
        }

#pragma unroll 1
    for (int it = 0; it < GITER; ++it) {
        const int g = wid + it * GSTRIDE;

        // ---- x fragments from prefetched regs ----
        short8 xf[2];
#pragma unroll
        for (int nt = 0; nt < 2; ++nt) {
            union { short8 v; unsigned d[4]; } f;
            f.v = zero8;
            if (lhi == 0) {
                f.d[0] = cvtpk(xr[nt][0], xr[nt][1]);
                f.d[1] = cvtpk(xr[nt][2], 1.0f);
            }
            xf[nt] = f.v;
        }
        // prefetch next group's x (hidden under L0..L2)
        if (it + 1 < GITER) {
            const int gn = g + GSTRIDE;
#pragma unroll
            for (int nt = 0; nt < 2; ++nt)
                if (lhi == 0) {
                    const float* xp = xg + ((size_t)gn*32 + 16*nt + l15) * 3;
                    xr[nt][0] = xp[0]; xr[nt][1] = xp[1]; xr[nt][2] = xp[2];
                }
        }

        // ---- layer 0 (swapped): D[o][r]; relu; b64 writes -> H ----
#pragma unroll
        for (int nt = 0; nt < 2; ++nt) {
            const int r = 16*nt + l15;
            const int swz = (r & 7) << 3;
#pragma unroll
            for (int mt = 0; mt < 4; ++mt) {
                float4v d = __builtin_amdgcn_mfma_f32_16x16x32_bf16(
                                b0f[mt], xf[nt], zero4, 0, 0, 0);
                uint2 p;
                p.x = cvtpk(fmaxf(d[0], 0.f), fmaxf(d[1], 0.f));
                p.y = cvtpk(fmaxf(d[2], 0.f), fmaxf(d[3], 0.f));
                *(uint2*)&H[(r*64 + 16*mt + 4*lhi) ^ swz] = p;
            }
        }

        // ---- layer 1 (swapped): B-frags from H (reads precede overwrites) ----
        short8 h1f[2][2];
#pragma unroll
        for (int nt = 0; nt < 2; ++nt) {
            const int r = 16*nt + l15;
            const int swz = (r & 7) << 3;
#pragma unroll
            for (int ks = 0; ks < 2; ++ks)
                h1f[nt][ks] = *(const short8*)&H[(r*64 + 32*ks + 8*lhi) ^ swz];
        }
#pragma unroll
        for (int nt = 0; nt < 2; ++nt) {
            const int r = 16*nt + l15;
            const int swz = (r & 7) << 3;
#pragma unroll
            for (int mt = 0; mt < 4; ++mt) {
                float4v a = __builtin_amdgcn_mfma_f32_16x16x32_bf16(
                                b1f[0][mt], h1f[nt][0], b1vv[mt], 0, 0, 0);
                a = __builtin_amdgcn_mfma_f32_16x16x32_bf16(
                                b1f[1][mt], h1f[nt][1], a, 0, 0, 0);
                uint2 p;
                p.x = cvtpk(fmaxf(a[0], 0.f), fmaxf(a[1], 0.f));
                p.y = cvtpk(fmaxf(a[2], 0.f), fmaxf(a[3], 0.f));
                *(uint2*)&H[(r*64 + 16*mt + 4*lhi) ^ swz] = p;
            }
        }

        // ---- layer 2 (unswapped): A-frags from H, B-frags from GLOBAL ----
        short8 a2[2][2];
#pragma unroll
        for (int m = 0; m < 2; ++m) {
            const int r = 16*m + l15;
            const int swz = (r & 7) << 3;
#pragma unroll
            for (int ks = 0; ks < 2; ++ks)
                a2[m][ks] = *(const short8*)&H[(r*64 + 32*ks + 8*lhi) ^ swz];
        }
        float* outp = feats + (size_t)g * 128;
#pragma unroll 2
        for (int n = 0; n < 8; ++n) {
            short8 w2f0 = *(const short8*)&w2p[n*1024 +  0];   // ks=0
            short8 w2f1 = *(const short8*)&w2p[n*1024 + 32];   // ks=1
            float4v c0 = __builtin_amdgcn_mfma_f32_16x16x32_bf16(
                             a2[0][0], w2f0, zero4, 0, 0, 0);
            c0 = __builtin_amdgcn_mfma_f32_16x16x32_bf16(
                             a2[0][1], w2f1, c0, 0, 0, 0);
            float4v c1 = __builtin_amdgcn_mfma_f32_16x16x32_bf16(
                             a2[1][0], w2f0, zero4, 0, 0, 0);
            c1 = __builtin_amdgcn_mfma_f32_16x16x32_bf16(
                             a2[1][1], w2f1, c1, 0, 0, 0);
            float v = fmaxf(fmaxf(fmaxf(c0[0], c0[1]), fmaxf(c0[2], c0[3])),
                            fmaxf(fmaxf(c1[0], c1[1]), fmaxf(c1[2], c1[3])));
            v = fmaxf(v, __shfl_xor(v, 16, 64));
            v = fmaxf(v, __shfl_xor(v, 32, 64));
            if (l < 16)
                outp[16*n + l15] = fmaxf(v + b2v[n], 0.f);   // bias+relu after max
        }
    }
}

extern "C" void kernel_launch(void* const* d_in, const int* in_sizes, int n_in,
                              void* d_out, int out_size, void* d_ws, size_t ws_size,
                              hipStream_t stream)
{
    const float* xg   = (const float*)d_in[0];
    const float* newx = (const float*)d_in[1];
    const float *W[3], *Bb[3], *G[3], *Be[3], *M[3], *V[3];
    for (int ll = 0; ll < 3; ++ll) {
        W[ll]  = (const float*)d_in[2 + 6*ll + 0];
        Bb[ll] = (const float*)d_in[2 + 6*ll + 1];
        G[ll]  = (const float*)d_in[2 + 6*ll + 2];
        Be[ll] = (const float*)d_in[2 + 6*ll + 3];
        M[ll]  = (const float*)d_in[2 + 6*ll + 4];
        V[ll]  = (const float*)d_in[2 + 6*ll + 5];
    }

    float* wsf = (float*)d_ws;

    fold_kernel<<<1, 256, 0, stream>>>(
        W[0], Bb[0], G[0], Be[0], M[0], V[0],
        W[1], Bb[1], G[1], Be[1], M[1], V[1],
        W[2], Bb[2], G[2], Be[2], M[2], V[2], wsf);

    copy_new_x<<<192, 256, 0, stream>>>((const float4*)newx, (float4*)d_out);

    float* feats = (float*)d_out + NEWX_ELEMS;
    sa_mfma_kernel<<<GRID, 256, 0, stream>>>(xg, wsf, feats);
}

// Round 12
// 110.574 us; speedup vs baseline: 2.0315x; 2.0315x over previous
//
#include <hip/hip_runtime.h>
#include <hip/hip_bf16.h>

#define EPS_BN 1e-5f

typedef __attribute__((ext_vector_type(8))) short short8;   // 8 x bf16 (4 VGPR)
typedef __attribute__((ext_vector_type(4))) float float4v;  // MFMA acc

constexpr int NGROUPS    = 65536;     // B*P = 16*4096
constexpr int NEWX_ELEMS = 196608;    // B*P*3
constexpr int GRID       = 8192;      // 4 waves/block, 2 groups/wave, GITER=1

// d_ws layout: f32 indices for folded f32 data, byte offsets for bf16 weights
constexpr int W0F = 0;      // f32[192]  W0' (64x3)
constexpr int B0F = 192;    // f32[64]
constexpr int B1F = 256;    // f32[64]
constexpr int B2F = 320;    // f32[128]
constexpr int W1B = 1792;   // bytes: ushort[4096]  W1' (64x64) bf16
constexpr int W2B = 10240;  // bytes: ushort[8192]  W2' (128x64) bf16

__device__ __forceinline__ unsigned short f2bf(float x) {
    return __builtin_bit_cast(unsigned short, __float2bfloat16(x));
}
__device__ __forceinline__ unsigned cvtpk(float a, float b) {
    unsigned r;
    asm("v_cvt_pk_bf16_f32 %0, %1, %2" : "=v"(r) : "v"(a), "v"(b));
    return r;
}

__global__ void fold_kernel(
    const float* w0, const float* b0, const float* g0,
    const float* be0, const float* m0, const float* v0,
    const float* w1, const float* b1, const float* g1,
    const float* be1, const float* m1, const float* v1,
    const float* w2, const float* b2, const float* g2,
    const float* be2, const float* m2, const float* v2,
    float* __restrict__ ws)
{
    const int t = threadIdx.x;
    ushort* w1b = (ushort*)((char*)ws + W1B);
    ushort* w2b = (ushort*)((char*)ws + W2B);
    if (t < 64) {
        float s0 = g0[t] * rsqrtf(v0[t] + EPS_BN);
        ws[B0F + t] = (b0[t] - m0[t]) * s0 + be0[t];
        ws[W0F + t*3 + 0] = w0[t*3 + 0] * s0;
        ws[W0F + t*3 + 1] = w0[t*3 + 1] * s0;
        ws[W0F + t*3 + 2] = w0[t*3 + 2] * s0;
        float s1 = g1[t] * rsqrtf(v1[t] + EPS_BN);
        ws[B1F + t] = (b1[t] - m1[t]) * s1 + be1[t];
    }
    if (t < 128) {
        float s2 = g2[t] * rsqrtf(v2[t] + EPS_BN);
        ws[B2F + t] = (b2[t] - m2[t]) * s2 + be2[t];
    }
    for (int i = t; i < 64*64; i += 256) {
        int o = i >> 6;
        float s = g1[o] * rsqrtf(v1[o] + EPS_BN);
        w1b[i] = f2bf(w1[i] * s);
    }
    for (int i = t; i < 128*64; i += 256) {
        int o = i >> 6;
        float s = g2[o] * rsqrtf(v2[o] + EPS_BN);
        w2b[i] = f2bf(w2[i] * s);
    }
}

// new_x passthrough, f32 -> f32
__global__ void copy_new_x(const float4* __restrict__ in, float4* __restrict__ out)
{
    int i = blockIdx.x * 256 + threadIdx.x;   // < 49,152
    out[i] = in[i];
}

// TWO groups per wave, straight-line (GITER=1): every phase runs two
// independent dependency chains (2x per-wave ILP at constant occupancy),
// and the two groups SHARE weight fragments -- the n-loop's 16 W2L
// ds_read_b128 amortize over 2 groups. W2 in block LDS (R11: global W2
// spills). Phases die in order (b0f after L0, b1f after L1) so peak live
// stays ~130 regs; lb(256,3) caps at ~170 (R10-proven no-spill).
__global__ __launch_bounds__(256, 3) void sa_mfma_kernel(
    const float* __restrict__ xg,
    const float* __restrict__ wsf,
    float* __restrict__ feats)
{
    __shared__ __align__(16) ushort W2L[8192];         // 16KB swizzled W2'
    __shared__ __align__(16) ushort Hs[4][2][2048];    // 4 waves x 2 grp x 4KB

    const int tid = threadIdx.x;
    const int w   = tid >> 6;
    const int l   = tid & 63;
    const int l15 = l & 15;
    const int lhi = l >> 4;

    const ushort* w1b = (const ushort*)((const char*)wsf + W1B);
    const ushort* w2b = (const ushort*)((const char*)wsf + W2B);

    // ---- stage W2' into LDS (granule = 16B; gi = o*8 + c/8; dst = gi^(o&7))
    {
        const uint4* src = (const uint4*)w2b;   // 1024 granules
        uint4* dst = (uint4*)W2L;
        for (int gi = tid; gi < 1024; gi += 256)
            dst[gi ^ ((gi >> 3) & 7)] = src[gi];
    }

    ushort* HA = Hs[w][0];
    ushort* HB = Hs[w][1];
    const short8  zero8 = {0,0,0,0,0,0,0,0};
    const float4v zero4 = {0.f, 0.f, 0.f, 0.f};

    const int wave_id = blockIdx.x * 4 + w;
    const int gA = wave_id * 2;
    const int gB = gA + 1;

    // ---- x loads (lanes lhi==0: sample = 16nt + l15) ----
    float xrA[2][3], xrB[2][3];
#pragma unroll
    for (int nt = 0; nt < 2; ++nt)
        if (lhi == 0) {
            const float* xa = xg + ((size_t)gA*32 + 16*nt + l15) * 3;
            xrA[nt][0] = xa[0]; xrA[nt][1] = xa[1]; xrA[nt][2] = xa[2];
            const float* xb = xg + ((size_t)gB*32 + 16*nt + l15) * 3;
            xrB[nt][0] = xb[0]; xrB[nt][1] = xb[1]; xrB[nt][2] = xb[2];
        }

    // ---- hoisted weight fragments ----
    short8 b0f[4];
#pragma unroll
    for (int mt = 0; mt < 4; ++mt) {
        union { short8 v; unsigned d[4]; } f;
        f.v = zero8;
        if (lhi == 0) {
            int o = 16*mt + l15;
            f.d[0] = cvtpk(wsf[W0F + o*3 + 0], wsf[W0F + o*3 + 1]);
            f.d[1] = cvtpk(wsf[W0F + o*3 + 2], wsf[B0F + o]);
        }
        b0f[mt] = f.v;
    }
    short8 b1f[2][4];
#pragma unroll
    for (int ks = 0; ks < 2; ++ks)
#pragma unroll
        for (int mt = 0; mt < 4; ++mt)
            b1f[ks][mt] = *(const short8*)&w1b[(16*mt + l15)*64 + 32*ks + 8*lhi];

    float4v b1vv[4];
#pragma unroll
    for (int mt = 0; mt < 4; ++mt)
        b1vv[mt] = *(const float4v*)&wsf[B1F + 16*mt + 4*lhi];
    float b2v[8];
#pragma unroll
    for (int n = 0; n < 8; ++n)
        b2v[n] = wsf[B2F + 16*n + l15];

    __syncthreads();   // W2L ready

    // ---- x fragments ----
    short8 xfA[2], xfB[2];
#pragma unroll
    for (int nt = 0; nt < 2; ++nt) {
        union { short8 v; unsigned d[4]; } fa, fb;
        fa.v = zero8; fb.v = zero8;
        if (lhi == 0) {
            fa.d[0] = cvtpk(xrA[nt][0], xrA[nt][1]);
            fa.d[1] = cvtpk(xrA[nt][2], 1.0f);
            fb.d[0] = cvtpk(xrB[nt][0], xrB[nt][1]);
            fb.d[1] = cvtpk(xrB[nt][2], 1.0f);
        }
        xfA[nt] = fa.v; xfB[nt] = fb.v;
    }

    // ---- layer 0 (swapped): two chains interleaved ----
#pragma unroll
    for (int nt = 0; nt < 2; ++nt) {
        const int r = 16*nt + l15;
        const int swz = (r & 7) << 3;
#pragma unroll
        for (int mt = 0; mt < 4; ++mt) {
            float4v dA = __builtin_amdgcn_mfma_f32_16x16x32_bf16(
                            b0f[mt], xfA[nt], zero4, 0, 0, 0);
            float4v dB = __builtin_amdgcn_mfma_f32_16x16x32_bf16(
                            b0f[mt], xfB[nt], zero4, 0, 0, 0);
            uint2 pA, pB;
            pA.x = cvtpk(fmaxf(dA[0], 0.f), fmaxf(dA[1], 0.f));
            pA.y = cvtpk(fmaxf(dA[2], 0.f), fmaxf(dA[3], 0.f));
            pB.x = cvtpk(fmaxf(dB[0], 0.f), fmaxf(dB[1], 0.f));
            pB.y = cvtpk(fmaxf(dB[2], 0.f), fmaxf(dB[3], 0.f));
            const int off = (r*64 + 16*mt + 4*lhi) ^ swz;
            *(uint2*)&HA[off] = pA;
            *(uint2*)&HB[off] = pB;
        }
    }

    // ---- layer 1 (swapped): both groups' B-frags, then interleaved MFMA ----
    short8 h1fA[2][2], h1fB[2][2];
#pragma unroll
    for (int nt = 0; nt < 2; ++nt) {
        const int r = 16*nt + l15;
        const int swz = (r & 7) << 3;
#pragma unroll
        for (int ks = 0; ks < 2; ++ks) {
            const int off = (r*64 + 32*ks + 8*lhi) ^ swz;
            h1fA[nt][ks] = *(const short8*)&HA[off];
            h1fB[nt][ks] = *(const short8*)&HB[off];
        }
    }
#pragma unroll
    for (int nt = 0; nt < 2; ++nt) {
        const int r = 16*nt + l15;
        const int swz = (r & 7) << 3;
#pragma unroll
        for (int mt = 0; mt < 4; ++mt) {
            float4v aA = __builtin_amdgcn_mfma_f32_16x16x32_bf16(
                            b1f[0][mt], h1fA[nt][0], b1vv[mt], 0, 0, 0);
            float4v aB = __builtin_amdgcn_mfma_f32_16x16x32_bf16(
                            b1f[0][mt], h1fB[nt][0], b1vv[mt], 0, 0, 0);
            aA = __builtin_amdgcn_mfma_f32_16x16x32_bf16(
                            b1f[1][mt], h1fA[nt][1], aA, 0, 0, 0);
            aB = __builtin_amdgcn_mfma_f32_16x16x32_bf16(
                            b1f[1][mt], h1fB[nt][1], aB, 0, 0, 0);
            uint2 pA, pB;
            pA.x = cvtpk(fmaxf(aA[0], 0.f), fmaxf(aA[1], 0.f));
            pA.y = cvtpk(fmaxf(aA[2], 0.f), fmaxf(aA[3], 0.f));
            pB.x = cvtpk(fmaxf(aB[0], 0.f), fmaxf(aB[1], 0.f));
            pB.y = cvtpk(fmaxf(aB[2], 0.f), fmaxf(aB[3], 0.f));
            const int off = (r*64 + 16*mt + 4*lhi) ^ swz;
            *(uint2*)&HA[off] = pA;
            *(uint2*)&HB[off] = pB;
        }
    }

    // ---- layer 2 (unswapped): shared W2 frags, two acc chains ----
    short8 a2A[2][2], a2B[2][2];
#pragma unroll
    for (int m = 0; m < 2; ++m) {
        const int r = 16*m + l15;
        const int swz = (r & 7) << 3;
#pragma unroll
        for (int ks = 0; ks < 2; ++ks) {
            const int off = (r*64 + 32*ks + 8*lhi) ^ swz;
            a2A[m][ks] = *(const short8*)&HA[off];
            a2B[m][ks] = *(const short8*)&HB[off];
        }
    }
    float* outpA = feats + (size_t)gA * 128;
    float* outpB = feats + (size_t)gB * 128;
    const int wswz = (l15 & 7) << 3;   // W2L read swizzle (o&7 == l15&7)

#pragma unroll 2
    for (int n = 0; n < 8; ++n) {
        short8 w2f0 = *(const short8*)&W2L[((16*n + l15)*64 +  0 + 8*lhi) ^ wswz];
        short8 w2f1 = *(const short8*)&W2L[((16*n + l15)*64 + 32 + 8*lhi) ^ wswz];
        float4v c0A = __builtin_amdgcn_mfma_f32_16x16x32_bf16(
                         a2A[0][0], w2f0, zero4, 0, 0, 0);
        float4v c0B = __builtin_amdgcn_mfma_f32_16x16x32_bf16(
                         a2B[0][0], w2f0, zero4, 0, 0, 0);
        c0A = __builtin_amdgcn_mfma_f32_16x16x32_bf16(a2A[0][1], w2f1, c0A, 0, 0, 0);
        c0B = __builtin_amdgcn_mfma_f32_16x16x32_bf16(a2B[0][1], w2f1, c0B, 0, 0, 0);
        float4v c1A = __builtin_amdgcn_mfma_f32_16x16x32_bf16(
                         a2A[1][0], w2f0, zero4, 0, 0, 0);
        float4v c1B = __builtin_amdgcn_mfma_f32_16x16x32_bf16(
                         a2B[1][0], w2f0, zero4, 0, 0, 0);
        c1A = __builtin_amdgcn_mfma_f32_16x16x32_bf16(a2A[1][1], w2f1, c1A, 0, 0, 0);
        c1B = __builtin_amdgcn_mfma_f32_16x16x32_bf16(a2B[1][1], w2f1, c1B, 0, 0, 0);

        float vA = fmaxf(fmaxf(fmaxf(c0A[0], c0A[1]), fmaxf(c0A[2], c0A[3])),
                         fmaxf(fmaxf(c1A[0], c1A[1]), fmaxf(c1A[2], c1A[3])));
        float vB = fmaxf(fmaxf(fmaxf(c0B[0], c0B[1]), fmaxf(c0B[2], c0B[3])),
                         fmaxf(fmaxf(c1B[0], c1B[1]), fmaxf(c1B[2], c1B[3])));
        vA = fmaxf(vA, __shfl_xor(vA, 16, 64));
        vA = fmaxf(vA, __shfl_xor(vA, 32, 64));
        vB = fmaxf(vB, __shfl_xor(vB, 16, 64));
        vB = fmaxf(vB, __shfl_xor(vB, 32, 64));
        if (l < 16) {
            outpA[16*n + l15] = fmaxf(vA + b2v[n], 0.f);
            outpB[16*n + l15] = fmaxf(vB + b2v[n], 0.f);
        }
    }
}

extern "C" void kernel_launch(void* const* d_in, const int* in_sizes, int n_in,
                              void* d_out, int out_size, void* d_ws, size_t ws_size,
                              hipStream_t stream)
{
    const float* xg   = (const float*)d_in[0];
    const float* newx = (const float*)d_in[1];
    const float *W[3], *Bb[3], *G[3], *Be[3], *M[3], *V[3];
    for (int ll = 0; ll < 3; ++ll) {
        W[ll]  = (const float*)d_in[2 + 6*ll + 0];
        Bb[ll] = (const float*)d_in[2 + 6*ll + 1];
        G[ll]  = (const float*)d_in[2 + 6*ll + 2];
        Be[ll] = (const float*)d_in[2 + 6*ll + 3];
        M[ll]  = (const float*)d_in[2 + 6*ll + 4];
        V[ll]  = (const float*)d_in[2 + 6*ll + 5];
    }

    float* wsf = (float*)d_ws;

    fold_kernel<<<1, 256, 0, stream>>>(
        W[0], Bb[0], G[0], Be[0], M[0], V[0],
        W[1], Bb[1], G[1], Be[1], M[1], V[1],
        W[2], Bb[2], G[2], Be[2], M[2], V[2], wsf);

    copy_new_x<<<192, 256, 0, stream>>>((const float4*)newx, (float4*)d_out);

    float* feats = (float*)d_out + NEWX_ELEMS;
    sa_mfma_kernel<<<GRID, 256, 0, stream>>>(xg, wsf, feats);
}